// Round 3
// baseline (1369.880 us; speedup 1.0000x reference)
//
#include <hip/hip_runtime.h>

#define CUTOFF 1.6f
#define BLOCK 256
#define EPT 8
#define EPB (BLOCK * EPT)

typedef float f32x4 __attribute__((ext_vector_type(4)));

__device__ __forceinline__ void nts1(float* p, float a) {
  __builtin_nontemporal_store(a, p);
}
__device__ __forceinline__ void nts4(float* p, float a, float b, float c,
                                     float d) {
  f32x4 w = {a, b, c, d};
  __builtin_nontemporal_store(w, (f32x4*)p);
}

// K1: read Rij, NT-write Rij passthrough, per-block short-range counts.
// Normal loads so Rij lines stay resident in LLC for K3's re-read.
__global__ void __launch_bounds__(BLOCK) k1_count_copy(
    const float* __restrict__ Rij, float* __restrict__ outRij,
    int* __restrict__ counts, long E)
{
  long b = blockIdx.x;
  int t = threadIdx.x;
  long base = b * (long)EPB + (long)t * EPT;
  int cnt = 0;
  if (base < E) {  // E % 8 == 0 -> thread has all 8 edges or none
    const f32x4* rp4 = (const f32x4*)(Rij + base * 3);
    float* op = outRij + base * 3;
    float rr[24];
#pragma unroll
    for (int q = 0; q < 6; ++q) {
      f32x4 v = rp4[q];
      __builtin_nontemporal_store(v, (f32x4*)(op + 4 * q));
      rr[4 * q + 0] = v.x; rr[4 * q + 1] = v.y;
      rr[4 * q + 2] = v.z; rr[4 * q + 3] = v.w;
    }
#pragma unroll
    for (int k = 0; k < EPT; ++k) {
      float x = rr[3 * k], y = rr[3 * k + 1], z = rr[3 * k + 2];
      float s = sqrtf(x * x + y * y + z * z);
      cnt += (s <= CUTOFF) ? 1 : 0;
    }
  }
#pragma unroll
  for (int d = 32; d > 0; d >>= 1) cnt += __shfl_down(cnt, d, 64);
  __shared__ int ssum;
  if (t == 0) ssum = 0;
  __syncthreads();
  if ((t & 63) == 0) atomicAdd(&ssum, cnt);
  __syncthreads();
  if (t == 0) counts[b] = ssum;
}

// K2: single-block exclusive scan of block counts (in place); writes n_sr
// (int to ws, float value to out[10E]).
__global__ void __launch_bounds__(1024) k2_scan(
    int* __restrict__ counts, int nb, int* __restrict__ nsr,
    float* __restrict__ out_nsr)
{
  int t = threadIdx.x;
  int C = (nb + 1023) >> 10;
  int start = t * C;
  int end = min(start + C, nb);
  int sum = 0;
  for (int i = start; i < end; ++i) sum += counts[i];
  int lane = t & 63, wid = t >> 6;
  int v = sum;
#pragma unroll
  for (int d = 1; d < 64; d <<= 1) {
    int n = __shfl_up(v, d, 64);
    if (lane >= d) v += n;
  }
  __shared__ int wsum[16];
  if (lane == 63) wsum[wid] = v;
  __syncthreads();
  int woff = 0;
  for (int w = 0; w < wid; ++w) woff += wsum[w];
  int run = woff + v - sum;  // exclusive prefix of this thread
  for (int i = start; i < end; ++i) {
    int c = counts[i];
    counts[i] = run;
    run += c;
  }
  if (t == 1023) {  // run here == grand total
    nsr[0] = run;
    out_nsr[0] = (float)run;
  }
}

// K3: idx passthrough (as float values), recompute mask, block scan, stable
// compacted scatter, plus per-block slice of the constant pad fills.
// All output writes are non-temporal.
__global__ void __launch_bounds__(BLOCK) k3_scatter_fill(
    const float* __restrict__ Rij, const int* __restrict__ idx_i,
    const int* __restrict__ idx_j, const int* __restrict__ offs,
    const int* __restrict__ nsr, float* __restrict__ out, long E, int nb)
{
  long b = blockIdx.x;
  int t = threadIdx.x;
  int lane = t & 63, wid = t >> 6;
  long base = b * (long)EPB + (long)t * EPT;
  long n = nsr[0];

  float rr[24];
  int ii[EPT], jj[EPT];
  unsigned m = 0;
  int cnt = 0;
  if (base < E) {
    const f32x4* rp4 = (const f32x4*)(Rij + base * 3);
#pragma unroll
    for (int q = 0; q < 6; ++q) {
      f32x4 v = rp4[q];
      rr[4 * q + 0] = v.x; rr[4 * q + 1] = v.y;
      rr[4 * q + 2] = v.z; rr[4 * q + 3] = v.w;
    }
    const int4* ip = (const int4*)(idx_i + base);
    const int4* jp = (const int4*)(idx_j + base);
    int4 ia = ip[0], ib = ip[1], ja = jp[0], jb = jp[1];
    ii[0] = ia.x; ii[1] = ia.y; ii[2] = ia.z; ii[3] = ia.w;
    ii[4] = ib.x; ii[5] = ib.y; ii[6] = ib.z; ii[7] = ib.w;
    jj[0] = ja.x; jj[1] = ja.y; jj[2] = ja.z; jj[3] = ja.w;
    jj[4] = jb.x; jj[5] = jb.y; jj[6] = jb.z; jj[7] = jb.w;
    // idx passthrough as float values (NT)
    nts4(out + 3 * E + base, (float)ii[0], (float)ii[1], (float)ii[2], (float)ii[3]);
    nts4(out + 3 * E + base + 4, (float)ii[4], (float)ii[5], (float)ii[6], (float)ii[7]);
    nts4(out + 4 * E + base, (float)jj[0], (float)jj[1], (float)jj[2], (float)jj[3]);
    nts4(out + 4 * E + base + 4, (float)jj[4], (float)jj[5], (float)jj[6], (float)jj[7]);
#pragma unroll
    for (int k = 0; k < EPT; ++k) {
      float x = rr[3 * k], y = rr[3 * k + 1], z = rr[3 * k + 2];
      float s = sqrtf(x * x + y * y + z * z);
      if (s <= CUTOFF) { m |= 1u << k; ++cnt; }
    }
  }

  // block scan of per-thread counts
  int sv = cnt;
#pragma unroll
  for (int d = 1; d < 64; d <<= 1) {
    int nn = __shfl_up(sv, d, 64);
    if (lane >= d) sv += nn;
  }
  __shared__ int wsum[BLOCK / 64];
  if (lane == 63) wsum[wid] = sv;
  __syncthreads();
  int woff = 0;
#pragma unroll
  for (int w = 0; w < BLOCK / 64; ++w)
    if (w < wid) woff += wsum[w];
  long pos = (long)offs[b] + woff + (sv - cnt);

  if (base < E && m) {
    float* srf = out + 5 * E;
    float* oi = out + 8 * E;
    float* oj = out + 9 * E;
#pragma unroll
    for (int k = 0; k < EPT; ++k) {
      if (m & (1u << k)) {
        nts1(srf + 3 * pos + 0, rr[3 * k + 0]);
        nts1(srf + 3 * pos + 1, rr[3 * k + 1]);
        nts1(srf + 3 * pos + 2, rr[3 * k + 2]);
        nts1(oi + pos, (float)ii[k]);
        nts1(oj + pos, (float)jj[k]);
        ++pos;
      }
    }
  }

  // pad fills: three flat constant ranges, sliced across blocks.
  // Rij_sr zeros: floats [5E+3n, 8E)
  {
    long len = 3 * (E - n);
    long share = (len + nb - 1) / nb;
    long lo = 5 * E + 3 * n + b * share;
    long hi = lo + share;
    long cap = 8 * E;
    if (hi > cap) hi = cap;
    for (long i = lo + t; i < hi; i += BLOCK) nts1(out + i, 0.0f);
  }
  // idx_i_sr pad = -1: floats [8E+n, 9E)
  {
    long len = E - n;
    long share = (len + nb - 1) / nb;
    long lo = 8 * E + n + b * share;
    long hi = lo + share;
    long cap = 9 * E;
    if (hi > cap) hi = cap;
    for (long i = lo + t; i < hi; i += BLOCK) nts1(out + i, -1.0f);
  }
  // idx_j_sr pad = -1: floats [9E+n, 10E)
  {
    long len = E - n;
    long share = (len + nb - 1) / nb;
    long lo = 9 * E + n + b * share;
    long hi = lo + share;
    long cap = 10 * E;
    if (hi > cap) hi = cap;
    for (long i = lo + t; i < hi; i += BLOCK) nts1(out + i, -1.0f);
  }
}

extern "C" void kernel_launch(void* const* d_in, const int* in_sizes, int n_in,
                              void* d_out, int out_size, void* d_ws,
                              size_t ws_size, hipStream_t stream)
{
  const float* Rij = (const float*)d_in[0];
  const int* idx_i = (const int*)d_in[1];
  const int* idx_j = (const int*)d_in[2];
  long E = (long)in_sizes[1];
  float* out = (float*)d_out;

  int nb = (int)((E + EPB - 1) / EPB);
  int* counts = (int*)d_ws;  // nb ints, fully rewritten by K1 every call
  int* nsr = counts + nb;    // 1 int, written by K2 every call

  k1_count_copy<<<nb, BLOCK, 0, stream>>>(Rij, out, counts, E);
  k2_scan<<<1, 1024, 0, stream>>>(counts, nb, nsr, out + 10 * E);
  k3_scatter_fill<<<nb, BLOCK, 0, stream>>>(Rij, idx_i, idx_j, counts, nsr,
                                            out, E, nb);
}

// Round 4
// 780.499 us; speedup vs baseline: 1.7551x; 1.7551x over previous
//
#include <hip/hip_runtime.h>

#define CUTOFF 1.6f
#define BLOCK 256
#define EPT 8
#define EPB (BLOCK * EPT)

typedef float f32x4 __attribute__((ext_vector_type(4)));

// K1: read Rij, NT-write Rij passthrough (full-line float4 only),
// per-block short-range counts. NT keeps Rij resident in L3 for K3.
__global__ void __launch_bounds__(BLOCK) k1_count_copy(
    const float* __restrict__ Rij, float* __restrict__ outRij,
    int* __restrict__ counts, long E)
{
  long b = blockIdx.x;
  int t = threadIdx.x;
  long base = b * (long)EPB + (long)t * EPT;
  int cnt = 0;
  if (base < E) {  // E % 8 == 0 -> thread has all 8 edges or none
    const f32x4* rp4 = (const f32x4*)(Rij + base * 3);
    float* op = outRij + base * 3;
    float rr[24];
#pragma unroll
    for (int q = 0; q < 6; ++q) {
      f32x4 v = rp4[q];
      __builtin_nontemporal_store(v, (f32x4*)(op + 4 * q));
      rr[4 * q + 0] = v.x; rr[4 * q + 1] = v.y;
      rr[4 * q + 2] = v.z; rr[4 * q + 3] = v.w;
    }
#pragma unroll
    for (int k = 0; k < EPT; ++k) {
      float x = rr[3 * k], y = rr[3 * k + 1], z = rr[3 * k + 2];
      float s = sqrtf(x * x + y * y + z * z);
      cnt += (s <= CUTOFF) ? 1 : 0;
    }
  }
#pragma unroll
  for (int d = 32; d > 0; d >>= 1) cnt += __shfl_down(cnt, d, 64);
  __shared__ int ssum;
  if (t == 0) ssum = 0;
  __syncthreads();
  if ((t & 63) == 0) atomicAdd(&ssum, cnt);
  __syncthreads();
  if (t == 0) counts[b] = ssum;
}

// K2: single-block exclusive scan of block counts (in place); writes n_sr
// (int to ws, float value to out[10E]).
__global__ void __launch_bounds__(1024) k2_scan(
    int* __restrict__ counts, int nb, int* __restrict__ nsr,
    float* __restrict__ out_nsr)
{
  int t = threadIdx.x;
  int C = (nb + 1023) >> 10;
  int start = t * C;
  int end = min(start + C, nb);
  int sum = 0;
  for (int i = start; i < end; ++i) sum += counts[i];
  int lane = t & 63, wid = t >> 6;
  int v = sum;
#pragma unroll
  for (int d = 1; d < 64; d <<= 1) {
    int n = __shfl_up(v, d, 64);
    if (lane >= d) v += n;
  }
  __shared__ int wsum[16];
  if (lane == 63) wsum[wid] = v;
  __syncthreads();
  int woff = 0;
  for (int w = 0; w < wid; ++w) woff += wsum[w];
  int run = woff + v - sum;  // exclusive prefix of this thread
  for (int i = start; i < end; ++i) {
    int c = counts[i];
    counts[i] = run;
    run += c;
  }
  if (t == 1023) {  // run here == grand total
    nsr[0] = run;
    out_nsr[0] = (float)run;
  }
}

// K3: idx passthrough (NT float4), recompute mask, block scan, stable
// compacted scatter (NORMAL stores - L2 merges them), fused pad fill
// (NORMAL stores).
__global__ void __launch_bounds__(BLOCK) k3_scatter_fill(
    const float* __restrict__ Rij, const int* __restrict__ idx_i,
    const int* __restrict__ idx_j, const int* __restrict__ offs,
    const int* __restrict__ nsr, float* __restrict__ out, long E, int nb)
{
  long b = blockIdx.x;
  int t = threadIdx.x;
  int lane = t & 63, wid = t >> 6;
  long base = b * (long)EPB + (long)t * EPT;
  long n = nsr[0];

  float rr[24];
  int ii[EPT], jj[EPT];
  unsigned m = 0;
  int cnt = 0;
  if (base < E) {
    const f32x4* rp4 = (const f32x4*)(Rij + base * 3);
#pragma unroll
    for (int q = 0; q < 6; ++q) {
      f32x4 v = rp4[q];
      rr[4 * q + 0] = v.x; rr[4 * q + 1] = v.y;
      rr[4 * q + 2] = v.z; rr[4 * q + 3] = v.w;
    }
    const int4* ip = (const int4*)(idx_i + base);
    const int4* jp = (const int4*)(idx_j + base);
    int4 ia = ip[0], ib = ip[1], ja = jp[0], jb = jp[1];
    ii[0] = ia.x; ii[1] = ia.y; ii[2] = ia.z; ii[3] = ia.w;
    ii[4] = ib.x; ii[5] = ib.y; ii[6] = ib.z; ii[7] = ib.w;
    jj[0] = ja.x; jj[1] = ja.y; jj[2] = ja.z; jj[3] = ja.w;
    jj[4] = jb.x; jj[5] = jb.y; jj[6] = jb.z; jj[7] = jb.w;
    // idx passthrough as float values; full-line NT float4
    f32x4 fi0 = {(float)ii[0], (float)ii[1], (float)ii[2], (float)ii[3]};
    f32x4 fi1 = {(float)ii[4], (float)ii[5], (float)ii[6], (float)ii[7]};
    f32x4 fj0 = {(float)jj[0], (float)jj[1], (float)jj[2], (float)jj[3]};
    f32x4 fj1 = {(float)jj[4], (float)jj[5], (float)jj[6], (float)jj[7]};
    __builtin_nontemporal_store(fi0, (f32x4*)(out + 3 * E + base));
    __builtin_nontemporal_store(fi1, (f32x4*)(out + 3 * E + base + 4));
    __builtin_nontemporal_store(fj0, (f32x4*)(out + 4 * E + base));
    __builtin_nontemporal_store(fj1, (f32x4*)(out + 4 * E + base + 4));
#pragma unroll
    for (int k = 0; k < EPT; ++k) {
      float x = rr[3 * k], y = rr[3 * k + 1], z = rr[3 * k + 2];
      float s = sqrtf(x * x + y * y + z * z);
      if (s <= CUTOFF) { m |= 1u << k; ++cnt; }
    }
  }

  // block scan of per-thread counts
  int sv = cnt;
#pragma unroll
  for (int d = 1; d < 64; d <<= 1) {
    int nn = __shfl_up(sv, d, 64);
    if (lane >= d) sv += nn;
  }
  __shared__ int wsum[BLOCK / 64];
  if (lane == 63) wsum[wid] = sv;
  __syncthreads();
  int woff = 0;
#pragma unroll
  for (int w = 0; w < BLOCK / 64; ++w)
    if (w < wid) woff += wsum[w];
  long pos = (long)offs[b] + woff + (sv - cnt);

  if (base < E && m) {
    float* srf = out + 5 * E;
    float* oi = out + 8 * E;
    float* oj = out + 9 * E;
#pragma unroll
    for (int k = 0; k < EPT; ++k) {
      if (m & (1u << k)) {
        srf[3 * pos + 0] = rr[3 * k + 0];
        srf[3 * pos + 1] = rr[3 * k + 1];
        srf[3 * pos + 2] = rr[3 * k + 2];
        oi[pos] = (float)ii[k];
        oj[pos] = (float)jj[k];
        ++pos;
      }
    }
  }

  // pad fills: three flat constant ranges, sliced across blocks (normal
  // stores; coalesced across the wave -> L2 merges into full lines).
  {
    long len = 3 * (E - n);
    long share = (len + nb - 1) / nb;
    long lo = 5 * E + 3 * n + b * share;
    long hi = lo + share;
    long cap = 8 * E;
    if (hi > cap) hi = cap;
    for (long i = lo + t; i < hi; i += BLOCK) out[i] = 0.0f;
  }
  {
    long len = E - n;
    long share = (len + nb - 1) / nb;
    long lo = 8 * E + n + b * share;
    long hi = lo + share;
    long cap = 9 * E;
    if (hi > cap) hi = cap;
    for (long i = lo + t; i < hi; i += BLOCK) out[i] = -1.0f;
  }
  {
    long len = E - n;
    long share = (len + nb - 1) / nb;
    long lo = 9 * E + n + b * share;
    long hi = lo + share;
    long cap = 10 * E;
    if (hi > cap) hi = cap;
    for (long i = lo + t; i < hi; i += BLOCK) out[i] = -1.0f;
  }
}

extern "C" void kernel_launch(void* const* d_in, const int* in_sizes, int n_in,
                              void* d_out, int out_size, void* d_ws,
                              size_t ws_size, hipStream_t stream)
{
  const float* Rij = (const float*)d_in[0];
  const int* idx_i = (const int*)d_in[1];
  const int* idx_j = (const int*)d_in[2];
  long E = (long)in_sizes[1];
  float* out = (float*)d_out;

  int nb = (int)((E + EPB - 1) / EPB);
  int* counts = (int*)d_ws;  // nb ints, fully rewritten by K1 every call
  int* nsr = counts + nb;    // 1 int, written by K2 every call

  k1_count_copy<<<nb, BLOCK, 0, stream>>>(Rij, out, counts, E);
  k2_scan<<<1, 1024, 0, stream>>>(counts, nb, nsr, out + 10 * E);
  k3_scatter_fill<<<nb, BLOCK, 0, stream>>>(Rij, idx_i, idx_j, counts, nsr,
                                            out, E, nb);
}

// Round 5
// 348.129 us; speedup vs baseline: 3.9350x; 2.2420x over previous
//
#include <hip/hip_runtime.h>

#define CUTOFF 1.6f
#define BLOCK 256
#define EPT 8
#define EPB (BLOCK * EPT)

typedef float f32x4 __attribute__((ext_vector_type(4)));

// K1: read Rij (float4), write Rij passthrough (normal stores — L2
// write-combines), per-block short-range counts.
__global__ void __launch_bounds__(BLOCK) k1_count_copy(
    const float* __restrict__ Rij, float* __restrict__ outRij,
    int* __restrict__ counts, long E)
{
  long b = blockIdx.x;
  int t = threadIdx.x;
  long base = b * (long)EPB + (long)t * EPT;
  int cnt = 0;
  if (base < E) {  // E % 8 == 0 -> thread has all 8 edges or none
    const f32x4* rp4 = (const f32x4*)(Rij + base * 3);
    f32x4* op4 = (f32x4*)(outRij + base * 3);
    float rr[24];
#pragma unroll
    for (int q = 0; q < 6; ++q) {
      f32x4 v = rp4[q];
      op4[q] = v;
      rr[4 * q + 0] = v.x; rr[4 * q + 1] = v.y;
      rr[4 * q + 2] = v.z; rr[4 * q + 3] = v.w;
    }
#pragma unroll
    for (int k = 0; k < EPT; ++k) {
      float x = rr[3 * k], y = rr[3 * k + 1], z = rr[3 * k + 2];
      float s = sqrtf(x * x + y * y + z * z);
      cnt += (s <= CUTOFF) ? 1 : 0;
    }
  }
#pragma unroll
  for (int d = 32; d > 0; d >>= 1) cnt += __shfl_down(cnt, d, 64);
  __shared__ int ssum;
  if (t == 0) ssum = 0;
  __syncthreads();
  if ((t & 63) == 0) atomicAdd(&ssum, cnt);
  __syncthreads();
  if (t == 0) counts[b] = ssum;
}

// K2: single-block exclusive scan of block counts (in place); writes n_sr
// (int to ws, float value to out[10E]).
__global__ void __launch_bounds__(1024) k2_scan(
    int* __restrict__ counts, int nb, int* __restrict__ nsr,
    float* __restrict__ out_nsr)
{
  int t = threadIdx.x;
  int C = (nb + 1023) >> 10;
  int start = t * C;
  int end = min(start + C, nb);
  int sum = 0;
  for (int i = start; i < end; ++i) sum += counts[i];
  int lane = t & 63, wid = t >> 6;
  int v = sum;
#pragma unroll
  for (int d = 1; d < 64; d <<= 1) {
    int n = __shfl_up(v, d, 64);
    if (lane >= d) v += n;
  }
  __shared__ int wsum[16];
  if (lane == 63) wsum[wid] = v;
  __syncthreads();
  int woff = 0;
  for (int w = 0; w < wid; ++w) woff += wsum[w];
  int run = woff + v - sum;  // exclusive prefix of this thread
  for (int i = start; i < end; ++i) {
    int c = counts[i];
    counts[i] = run;
    run += c;
  }
  if (t == 1023) {  // run here == grand total
    nsr[0] = run;
    out_nsr[0] = (float)run;
  }
}

// K3: idx passthrough (float4, normal stores), recompute mask, block scan,
// stable compacted scatter (normal stores), fused pad fill (normal stores).
__global__ void __launch_bounds__(BLOCK) k3_scatter_fill(
    const float* __restrict__ Rij, const int* __restrict__ idx_i,
    const int* __restrict__ idx_j, const int* __restrict__ offs,
    const int* __restrict__ nsr, float* __restrict__ out, long E, int nb)
{
  long b = blockIdx.x;
  int t = threadIdx.x;
  int lane = t & 63, wid = t >> 6;
  long base = b * (long)EPB + (long)t * EPT;
  long n = nsr[0];

  float rr[24];
  int ii[EPT], jj[EPT];
  unsigned m = 0;
  int cnt = 0;
  if (base < E) {
    const f32x4* rp4 = (const f32x4*)(Rij + base * 3);
#pragma unroll
    for (int q = 0; q < 6; ++q) {
      f32x4 v = rp4[q];
      rr[4 * q + 0] = v.x; rr[4 * q + 1] = v.y;
      rr[4 * q + 2] = v.z; rr[4 * q + 3] = v.w;
    }
    const int4* ip = (const int4*)(idx_i + base);
    const int4* jp = (const int4*)(idx_j + base);
    int4 ia = ip[0], ib = ip[1], ja = jp[0], jb = jp[1];
    ii[0] = ia.x; ii[1] = ia.y; ii[2] = ia.z; ii[3] = ia.w;
    ii[4] = ib.x; ii[5] = ib.y; ii[6] = ib.z; ii[7] = ib.w;
    jj[0] = ja.x; jj[1] = ja.y; jj[2] = ja.z; jj[3] = ja.w;
    jj[4] = jb.x; jj[5] = jb.y; jj[6] = jb.z; jj[7] = jb.w;
    // idx passthrough as float values (normal float4 stores)
    f32x4 fi0 = {(float)ii[0], (float)ii[1], (float)ii[2], (float)ii[3]};
    f32x4 fi1 = {(float)ii[4], (float)ii[5], (float)ii[6], (float)ii[7]};
    f32x4 fj0 = {(float)jj[0], (float)jj[1], (float)jj[2], (float)jj[3]};
    f32x4 fj1 = {(float)jj[4], (float)jj[5], (float)jj[6], (float)jj[7]};
    *(f32x4*)(out + 3 * E + base) = fi0;
    *(f32x4*)(out + 3 * E + base + 4) = fi1;
    *(f32x4*)(out + 4 * E + base) = fj0;
    *(f32x4*)(out + 4 * E + base + 4) = fj1;
#pragma unroll
    for (int k = 0; k < EPT; ++k) {
      float x = rr[3 * k], y = rr[3 * k + 1], z = rr[3 * k + 2];
      float s = sqrtf(x * x + y * y + z * z);
      if (s <= CUTOFF) { m |= 1u << k; ++cnt; }
    }
  }

  // block scan of per-thread counts
  int sv = cnt;
#pragma unroll
  for (int d = 1; d < 64; d <<= 1) {
    int nn = __shfl_up(sv, d, 64);
    if (lane >= d) sv += nn;
  }
  __shared__ int wsum[BLOCK / 64];
  if (lane == 63) wsum[wid] = sv;
  __syncthreads();
  int woff = 0;
#pragma unroll
  for (int w = 0; w < BLOCK / 64; ++w)
    if (w < wid) woff += wsum[w];
  long pos = (long)offs[b] + woff + (sv - cnt);

  if (base < E && m) {
    float* srf = out + 5 * E;
    float* oi = out + 8 * E;
    float* oj = out + 9 * E;
#pragma unroll
    for (int k = 0; k < EPT; ++k) {
      if (m & (1u << k)) {
        srf[3 * pos + 0] = rr[3 * k + 0];
        srf[3 * pos + 1] = rr[3 * k + 1];
        srf[3 * pos + 2] = rr[3 * k + 2];
        oi[pos] = (float)ii[k];
        oj[pos] = (float)jj[k];
        ++pos;
      }
    }
  }

  // pad fills: three flat constant ranges, sliced across blocks.
  {
    long len = 3 * (E - n);
    long share = (len + nb - 1) / nb;
    long lo = 5 * E + 3 * n + b * share;
    long hi = lo + share;
    long cap = 8 * E;
    if (hi > cap) hi = cap;
    for (long i = lo + t; i < hi; i += BLOCK) out[i] = 0.0f;
  }
  {
    long len = E - n;
    long share = (len + nb - 1) / nb;
    long lo = 8 * E + n + b * share;
    long hi = lo + share;
    long cap = 9 * E;
    if (hi > cap) hi = cap;
    for (long i = lo + t; i < hi; i += BLOCK) out[i] = -1.0f;
  }
  {
    long len = E - n;
    long share = (len + nb - 1) / nb;
    long lo = 9 * E + n + b * share;
    long hi = lo + share;
    long cap = 10 * E;
    if (hi > cap) hi = cap;
    for (long i = lo + t; i < hi; i += BLOCK) out[i] = -1.0f;
  }
}

extern "C" void kernel_launch(void* const* d_in, const int* in_sizes, int n_in,
                              void* d_out, int out_size, void* d_ws,
                              size_t ws_size, hipStream_t stream)
{
  const float* Rij = (const float*)d_in[0];
  const int* idx_i = (const int*)d_in[1];
  const int* idx_j = (const int*)d_in[2];
  long E = (long)in_sizes[1];
  float* out = (float*)d_out;

  int nb = (int)((E + EPB - 1) / EPB);
  int* counts = (int*)d_ws;  // nb ints, fully rewritten by K1 every call
  int* nsr = counts + nb;    // 1 int, written by K2 every call

  k1_count_copy<<<nb, BLOCK, 0, stream>>>(Rij, out, counts, E);
  k2_scan<<<1, 1024, 0, stream>>>(counts, nb, nsr, out + 10 * E);
  k3_scatter_fill<<<nb, BLOCK, 0, stream>>>(Rij, idx_i, idx_j, counts, nsr,
                                            out, E, nb);
}

// Round 6
// 305.085 us; speedup vs baseline: 4.4902x; 1.1411x over previous
//
#include <hip/hip_runtime.h>

#define CUTOFF 1.6f
#define BLOCK 256
#define EPT 8
#define EPB (BLOCK * EPT)

typedef float f32x4 __attribute__((ext_vector_type(4)));

// K1: read Rij (float4), write Rij passthrough, per-block counts.
__global__ void __launch_bounds__(BLOCK) k1_count_copy(
    const float* __restrict__ Rij, float* __restrict__ outRij,
    int* __restrict__ counts, long E)
{
  long b = blockIdx.x;
  int t = threadIdx.x;
  long base = b * (long)EPB + (long)t * EPT;
  int cnt = 0;
  if (base < E) {  // E % 8 == 0 -> thread has all 8 edges or none
    const f32x4* rp4 = (const f32x4*)(Rij + base * 3);
    f32x4* op4 = (f32x4*)(outRij + base * 3);
    float rr[24];
#pragma unroll
    for (int q = 0; q < 6; ++q) {
      f32x4 v = rp4[q];
      op4[q] = v;
      rr[4 * q + 0] = v.x; rr[4 * q + 1] = v.y;
      rr[4 * q + 2] = v.z; rr[4 * q + 3] = v.w;
    }
#pragma unroll
    for (int k = 0; k < EPT; ++k) {
      float x = rr[3 * k], y = rr[3 * k + 1], z = rr[3 * k + 2];
      float s = sqrtf(x * x + y * y + z * z);
      cnt += (s <= CUTOFF) ? 1 : 0;
    }
  }
#pragma unroll
  for (int d = 32; d > 0; d >>= 1) cnt += __shfl_down(cnt, d, 64);
  __shared__ int ssum;
  if (t == 0) ssum = 0;
  __syncthreads();
  if ((t & 63) == 0) atomicAdd(&ssum, cnt);
  __syncthreads();
  if (t == 0) counts[b] = ssum;
}

// K2: single-block exclusive scan of block counts (in place); writes n_sr.
__global__ void __launch_bounds__(1024) k2_scan(
    int* __restrict__ counts, int nb, int* __restrict__ nsr,
    float* __restrict__ out_nsr)
{
  int t = threadIdx.x;
  int C = (nb + 1023) >> 10;
  int start = t * C;
  int end = min(start + C, nb);
  int sum = 0;
  for (int i = start; i < end; ++i) sum += counts[i];
  int lane = t & 63, wid = t >> 6;
  int v = sum;
#pragma unroll
  for (int d = 1; d < 64; d <<= 1) {
    int n = __shfl_up(v, d, 64);
    if (lane >= d) v += n;
  }
  __shared__ int wsum[16];
  if (lane == 63) wsum[wid] = v;
  __syncthreads();
  int woff = 0;
  for (int w = 0; w < wid; ++w) woff += wsum[w];
  int run = woff + v - sum;  // exclusive prefix of this thread
  for (int i = start; i < end; ++i) {
    int c = counts[i];
    counts[i] = run;
    run += c;
  }
  if (t == 1023) {  // run here == grand total
    nsr[0] = run;
    out_nsr[0] = (float)run;
  }
}

// cooperative aligned copy: dst[0..len) = src[0..len), float4 interior
__device__ __forceinline__ void coop_copy(float* __restrict__ dst,
                                          const float* __restrict__ src,
                                          int len, int t)
{
  int h = (int)(((16u - (unsigned)((unsigned long long)dst & 15ull)) >> 2) & 3u);
  if (h > len) h = len;
  if (t < h) dst[t] = src[t];
  int n4 = (len - h) >> 2;
  f32x4* d4 = (f32x4*)(dst + h);
  for (int q = t; q < n4; q += BLOCK) {
    int s = h + 4 * q;
    f32x4 v = {src[s], src[s + 1], src[s + 2], src[s + 3]};
    d4[q] = v;
  }
  int done = h + 4 * n4;
  int rem = len - done;
  if (t < rem) dst[done + t] = src[done + t];
}

// cooperative aligned constant fill over absolute float range [lo,hi)
__device__ __forceinline__ void coop_fill(float* __restrict__ base, long lo,
                                          long hi, float val, int t)
{
  long len = hi - lo;
  if (len <= 0) return;
  float* p = base + lo;
  int h = (int)(((16u - (unsigned)((unsigned long long)p & 15ull)) >> 2) & 3u);
  if ((long)h > len) h = (int)len;
  if (t < h) p[t] = val;
  long n4 = (len - h) >> 2;
  f32x4* d4 = (f32x4*)(p + h);
  f32x4 v = {val, val, val, val};
  for (long q = t; q < n4; q += BLOCK) d4[q] = v;
  long done = h + 4 * n4;
  int rem = (int)(len - done);
  if (t < rem) p[done + t] = val;
}

// K3: idx passthrough (float4), mask + block scan, LDS-staged compaction,
// aligned cooperative float4 output writes, fused vectorized pad fill.
__global__ void __launch_bounds__(BLOCK) k3_scatter_fill(
    const float* __restrict__ Rij, const int* __restrict__ idx_i,
    const int* __restrict__ idx_j, const int* __restrict__ offs,
    const int* __restrict__ nsr, float* __restrict__ out, long E, int nb)
{
  long b = blockIdx.x;
  int t = threadIdx.x;
  int lane = t & 63, wid = t >> 6;
  long base = b * (long)EPB + (long)t * EPT;
  long n = nsr[0];

  __shared__ float sR[3 * EPB];  // 24 KB
  __shared__ float sI[EPB];      // 8 KB
  __shared__ float sJ[EPB];      // 8 KB
  __shared__ int wsum[BLOCK / 64];

  float rr[24];
  int ii[EPT], jj[EPT];
  unsigned m = 0;
  int cnt = 0;
  if (base < E) {
    const f32x4* rp4 = (const f32x4*)(Rij + base * 3);
#pragma unroll
    for (int q = 0; q < 6; ++q) {
      f32x4 v = rp4[q];
      rr[4 * q + 0] = v.x; rr[4 * q + 1] = v.y;
      rr[4 * q + 2] = v.z; rr[4 * q + 3] = v.w;
    }
    const int4* ip = (const int4*)(idx_i + base);
    const int4* jp = (const int4*)(idx_j + base);
    int4 ia = ip[0], ib = ip[1], ja = jp[0], jb = jp[1];
    ii[0] = ia.x; ii[1] = ia.y; ii[2] = ia.z; ii[3] = ia.w;
    ii[4] = ib.x; ii[5] = ib.y; ii[6] = ib.z; ii[7] = ib.w;
    jj[0] = ja.x; jj[1] = ja.y; jj[2] = ja.z; jj[3] = ja.w;
    jj[4] = jb.x; jj[5] = jb.y; jj[6] = jb.z; jj[7] = jb.w;
    // idx passthrough as float values (normal float4 stores)
    f32x4 fi0 = {(float)ii[0], (float)ii[1], (float)ii[2], (float)ii[3]};
    f32x4 fi1 = {(float)ii[4], (float)ii[5], (float)ii[6], (float)ii[7]};
    f32x4 fj0 = {(float)jj[0], (float)jj[1], (float)jj[2], (float)jj[3]};
    f32x4 fj1 = {(float)jj[4], (float)jj[5], (float)jj[6], (float)jj[7]};
    *(f32x4*)(out + 3 * E + base) = fi0;
    *(f32x4*)(out + 3 * E + base + 4) = fi1;
    *(f32x4*)(out + 4 * E + base) = fj0;
    *(f32x4*)(out + 4 * E + base + 4) = fj1;
#pragma unroll
    for (int k = 0; k < EPT; ++k) {
      float x = rr[3 * k], y = rr[3 * k + 1], z = rr[3 * k + 2];
      float s = sqrtf(x * x + y * y + z * z);
      if (s <= CUTOFF) { m |= 1u << k; ++cnt; }
    }
  }

  // block scan of per-thread counts
  int sv = cnt;
#pragma unroll
  for (int d = 1; d < 64; d <<= 1) {
    int nn = __shfl_up(sv, d, 64);
    if (lane >= d) sv += nn;
  }
  if (lane == 63) wsum[wid] = sv;
  __syncthreads();
  int woff = 0, bsum = 0;
#pragma unroll
  for (int w = 0; w < BLOCK / 64; ++w) {
    int s = wsum[w];
    if (w < wid) woff += s;
    bsum += s;
  }
  int texcl = woff + sv - cnt;  // thread's exclusive offset within block

  // stage compacted edges into LDS in stable order
  if (base < E && m) {
    int p = texcl;
#pragma unroll
    for (int k = 0; k < EPT; ++k) {
      if (m & (1u << k)) {
        sR[3 * p + 0] = rr[3 * k + 0];
        sR[3 * p + 1] = rr[3 * k + 1];
        sR[3 * p + 2] = rr[3 * k + 2];
        sI[p] = (float)ii[k];
        sJ[p] = (float)jj[k];
        ++p;
      }
    }
  }
  __syncthreads();

  // cooperative aligned writes of the block's three contiguous runs
  long off = offs[b];
  coop_copy(out + 5 * E + 3 * off, sR, 3 * bsum, t);
  coop_copy(out + 8 * E + off, sI, bsum, t);
  coop_copy(out + 9 * E + off, sJ, bsum, t);

  // pad fills: three flat constant ranges, sliced across blocks, float4.
  {
    long len = 3 * (E - n);
    long share = ((len + nb - 1) / nb + 3) & ~3L;
    long lo = 5 * E + 3 * n + b * share;
    long hi = lo + share;
    long cap = 8 * E;
    if (hi > cap) hi = cap;
    coop_fill(out, lo, hi, 0.0f, t);
  }
  {
    long len = E - n;
    long share = ((len + nb - 1) / nb + 3) & ~3L;
    long lo = 8 * E + n + b * share;
    long hi = lo + share;
    long cap = 9 * E;
    if (hi > cap) hi = cap;
    coop_fill(out, lo, hi, -1.0f, t);
  }
  {
    long len = E - n;
    long share = ((len + nb - 1) / nb + 3) & ~3L;
    long lo = 9 * E + n + b * share;
    long hi = lo + share;
    long cap = 10 * E;
    if (hi > cap) hi = cap;
    coop_fill(out, lo, hi, -1.0f, t);
  }
}

extern "C" void kernel_launch(void* const* d_in, const int* in_sizes, int n_in,
                              void* d_out, int out_size, void* d_ws,
                              size_t ws_size, hipStream_t stream)
{
  const float* Rij = (const float*)d_in[0];
  const int* idx_i = (const int*)d_in[1];
  const int* idx_j = (const int*)d_in[2];
  long E = (long)in_sizes[1];
  float* out = (float*)d_out;

  int nb = (int)((E + EPB - 1) / EPB);
  int* counts = (int*)d_ws;  // nb ints, fully rewritten by K1 every call
  int* nsr = counts + nb;    // 1 int, written by K2 every call

  k1_count_copy<<<nb, BLOCK, 0, stream>>>(Rij, out, counts, E);
  k2_scan<<<1, 1024, 0, stream>>>(counts, nb, nsr, out + 10 * E);
  k3_scatter_fill<<<nb, BLOCK, 0, stream>>>(Rij, idx_i, idx_j, counts, nsr,
                                            out, E, nb);
}

// Round 7
// 304.258 us; speedup vs baseline: 4.5024x; 1.0027x over previous
//
#include <hip/hip_runtime.h>

#define CUTOFF 1.6f
#define BLOCK 256
#define EPT 4
#define EPB (BLOCK * EPT)

typedef float f32x4 __attribute__((ext_vector_type(4)));

// K1: read Rij (float4), write Rij passthrough, per-block counts.
__global__ void __launch_bounds__(BLOCK) k1_count_copy(
    const float* __restrict__ Rij, float* __restrict__ outRij,
    int* __restrict__ counts, long E)
{
  long b = blockIdx.x;
  int t = threadIdx.x;
  long base = b * (long)EPB + (long)t * EPT;
  int cnt = 0;
  if (base < E) {  // E % 4 == 0 -> thread has all 4 edges or none
    const f32x4* rp4 = (const f32x4*)(Rij + base * 3);
    f32x4* op4 = (f32x4*)(outRij + base * 3);
    float rr[12];
#pragma unroll
    for (int q = 0; q < 3; ++q) {
      f32x4 v = rp4[q];
      op4[q] = v;
      rr[4 * q + 0] = v.x; rr[4 * q + 1] = v.y;
      rr[4 * q + 2] = v.z; rr[4 * q + 3] = v.w;
    }
#pragma unroll
    for (int k = 0; k < EPT; ++k) {
      float x = rr[3 * k], y = rr[3 * k + 1], z = rr[3 * k + 2];
      float s = sqrtf(x * x + y * y + z * z);
      cnt += (s <= CUTOFF) ? 1 : 0;
    }
  }
#pragma unroll
  for (int d = 32; d > 0; d >>= 1) cnt += __shfl_down(cnt, d, 64);
  __shared__ int ssum;
  if (t == 0) ssum = 0;
  __syncthreads();
  if ((t & 63) == 0) atomicAdd(&ssum, cnt);
  __syncthreads();
  if (t == 0) counts[b] = ssum;
}

// K2: single-block exclusive scan of block counts (in place); writes n_sr.
__global__ void __launch_bounds__(1024) k2_scan(
    int* __restrict__ counts, int nb, int* __restrict__ nsr,
    float* __restrict__ out_nsr)
{
  int t = threadIdx.x;
  int C = (nb + 1023) >> 10;
  int start = t * C;
  int end = min(start + C, nb);
  int sum = 0;
  for (int i = start; i < end; ++i) sum += counts[i];
  int lane = t & 63, wid = t >> 6;
  int v = sum;
#pragma unroll
  for (int d = 1; d < 64; d <<= 1) {
    int n = __shfl_up(v, d, 64);
    if (lane >= d) v += n;
  }
  __shared__ int wsum[16];
  if (lane == 63) wsum[wid] = v;
  __syncthreads();
  int woff = 0;
  for (int w = 0; w < wid; ++w) woff += wsum[w];
  int run = woff + v - sum;  // exclusive prefix of this thread
  for (int i = start; i < end; ++i) {
    int c = counts[i];
    counts[i] = run;
    run += c;
  }
  if (t == 1023) {  // run here == grand total
    nsr[0] = run;
    out_nsr[0] = (float)run;
  }
}

// cooperative aligned copy: dst[0..len) = src[0..len), float4 interior
__device__ __forceinline__ void coop_copy(float* __restrict__ dst,
                                          const float* __restrict__ src,
                                          int len, int t)
{
  int h = (int)(((16u - (unsigned)((unsigned long long)dst & 15ull)) >> 2) & 3u);
  if (h > len) h = len;
  if (t < h) dst[t] = src[t];
  int n4 = (len - h) >> 2;
  f32x4* d4 = (f32x4*)(dst + h);
  for (int q = t; q < n4; q += BLOCK) {
    int s = h + 4 * q;
    f32x4 v = {src[s], src[s + 1], src[s + 2], src[s + 3]};
    d4[q] = v;
  }
  int done = h + 4 * n4;
  int rem = len - done;
  if (t < rem) dst[done + t] = src[done + t];
}

// cooperative aligned constant fill over absolute float range [lo,hi)
__device__ __forceinline__ void coop_fill(float* __restrict__ base, long lo,
                                          long hi, float val, int t)
{
  long len = hi - lo;
  if (len <= 0) return;
  float* p = base + lo;
  int h = (int)(((16u - (unsigned)((unsigned long long)p & 15ull)) >> 2) & 3u);
  if ((long)h > len) h = (int)len;
  if (t < h) p[t] = val;
  long n4 = (len - h) >> 2;
  f32x4* d4 = (f32x4*)(p + h);
  f32x4 v = {val, val, val, val};
  for (long q = t; q < n4; q += BLOCK) d4[q] = v;
  long done = h + 4 * n4;
  int rem = (int)(len - done);
  if (t < rem) p[done + t] = val;
}

// K3: idx passthrough (float4), mask + block scan, LDS-staged compaction
// (20 KB -> 8 blocks/CU, full occupancy), aligned cooperative float4 output
// writes, fused vectorized pad fill.
__global__ void __launch_bounds__(BLOCK) k3_scatter_fill(
    const float* __restrict__ Rij, const int* __restrict__ idx_i,
    const int* __restrict__ idx_j, const int* __restrict__ offs,
    const int* __restrict__ nsr, float* __restrict__ out, long E, int nb)
{
  long b = blockIdx.x;
  int t = threadIdx.x;
  int lane = t & 63, wid = t >> 6;
  long base = b * (long)EPB + (long)t * EPT;
  long n = nsr[0];

  __shared__ float sR[3 * EPB];  // 12 KB
  __shared__ float sI[EPB];      // 4 KB
  __shared__ float sJ[EPB];      // 4 KB
  __shared__ int wsum[BLOCK / 64];

  float rr[12];
  int ii[EPT], jj[EPT];
  unsigned m = 0;
  int cnt = 0;
  if (base < E) {
    const f32x4* rp4 = (const f32x4*)(Rij + base * 3);
#pragma unroll
    for (int q = 0; q < 3; ++q) {
      f32x4 v = rp4[q];
      rr[4 * q + 0] = v.x; rr[4 * q + 1] = v.y;
      rr[4 * q + 2] = v.z; rr[4 * q + 3] = v.w;
    }
    int4 ia = *(const int4*)(idx_i + base);
    int4 ja = *(const int4*)(idx_j + base);
    ii[0] = ia.x; ii[1] = ia.y; ii[2] = ia.z; ii[3] = ia.w;
    jj[0] = ja.x; jj[1] = ja.y; jj[2] = ja.z; jj[3] = ja.w;
    // idx passthrough as float values (normal float4 stores)
    f32x4 fi0 = {(float)ii[0], (float)ii[1], (float)ii[2], (float)ii[3]};
    f32x4 fj0 = {(float)jj[0], (float)jj[1], (float)jj[2], (float)jj[3]};
    *(f32x4*)(out + 3 * E + base) = fi0;
    *(f32x4*)(out + 4 * E + base) = fj0;
#pragma unroll
    for (int k = 0; k < EPT; ++k) {
      float x = rr[3 * k], y = rr[3 * k + 1], z = rr[3 * k + 2];
      float s = sqrtf(x * x + y * y + z * z);
      if (s <= CUTOFF) { m |= 1u << k; ++cnt; }
    }
  }

  // block scan of per-thread counts
  int sv = cnt;
#pragma unroll
  for (int d = 1; d < 64; d <<= 1) {
    int nn = __shfl_up(sv, d, 64);
    if (lane >= d) sv += nn;
  }
  if (lane == 63) wsum[wid] = sv;
  __syncthreads();
  int woff = 0, bsum = 0;
#pragma unroll
  for (int w = 0; w < BLOCK / 64; ++w) {
    int s = wsum[w];
    if (w < wid) woff += s;
    bsum += s;
  }
  int texcl = woff + sv - cnt;  // thread's exclusive offset within block

  // stage compacted edges into LDS in stable order
  if (base < E && m) {
    int p = texcl;
#pragma unroll
    for (int k = 0; k < EPT; ++k) {
      if (m & (1u << k)) {
        sR[3 * p + 0] = rr[3 * k + 0];
        sR[3 * p + 1] = rr[3 * k + 1];
        sR[3 * p + 2] = rr[3 * k + 2];
        sI[p] = (float)ii[k];
        sJ[p] = (float)jj[k];
        ++p;
      }
    }
  }
  __syncthreads();

  // cooperative aligned writes of the block's three contiguous runs
  long off = offs[b];
  coop_copy(out + 5 * E + 3 * off, sR, 3 * bsum, t);
  coop_copy(out + 8 * E + off, sI, bsum, t);
  coop_copy(out + 9 * E + off, sJ, bsum, t);

  // pad fills: three flat constant ranges, sliced across blocks, float4.
  {
    long len = 3 * (E - n);
    long share = ((len + nb - 1) / nb + 3) & ~3L;
    long lo = 5 * E + 3 * n + b * share;
    long hi = lo + share;
    long cap = 8 * E;
    if (hi > cap) hi = cap;
    coop_fill(out, lo, hi, 0.0f, t);
  }
  {
    long len = E - n;
    long share = ((len + nb - 1) / nb + 3) & ~3L;
    long lo = 8 * E + n + b * share;
    long hi = lo + share;
    long cap = 9 * E;
    if (hi > cap) hi = cap;
    coop_fill(out, lo, hi, -1.0f, t);
  }
  {
    long len = E - n;
    long share = ((len + nb - 1) / nb + 3) & ~3L;
    long lo = 9 * E + n + b * share;
    long hi = lo + share;
    long cap = 10 * E;
    if (hi > cap) hi = cap;
    coop_fill(out, lo, hi, -1.0f, t);
  }
}

extern "C" void kernel_launch(void* const* d_in, const int* in_sizes, int n_in,
                              void* d_out, int out_size, void* d_ws,
                              size_t ws_size, hipStream_t stream)
{
  const float* Rij = (const float*)d_in[0];
  const int* idx_i = (const int*)d_in[1];
  const int* idx_j = (const int*)d_in[2];
  long E = (long)in_sizes[1];
  float* out = (float*)d_out;

  int nb = (int)((E + EPB - 1) / EPB);
  int* counts = (int*)d_ws;  // nb ints, fully rewritten by K1 every call
  int* nsr = counts + nb;    // 1 int, written by K2 every call

  k1_count_copy<<<nb, BLOCK, 0, stream>>>(Rij, out, counts, E);
  k2_scan<<<1, 1024, 0, stream>>>(counts, nb, nsr, out + 10 * E);
  k3_scatter_fill<<<nb, BLOCK, 0, stream>>>(Rij, idx_i, idx_j, counts, nsr,
                                            out, E, nb);
}